// Round 2
// baseline (452.311 us; speedup 1.0000x reference)
//
#include <hip/hip_runtime.h>
#include <stdint.h>

// Bitwise NAND/NOR bipartite layer:
//   out[i] = ~( nor_mask[i] ? (A[idx[i,0]] | A[idx[i,1]])
//                           : (A[idx[i,0]] & A[idx[i,1]]) )
// A: [32768 x 2048] int32 rows (8 KB each). Memory-bound gather+bitop.
//
// Two-kernel structure: a one-shot decode kernel resolves the harness's
// upload formats (idx int32 vs int64, mask int32 vs byte-bool) ONCE and
// writes per-row packed byte offsets into d_ws; the main kernel is then
// pure gather + bitop + nontemporal store with a 2-scalar-load prologue.

typedef int int4v __attribute__((ext_vector_type(4)));

#define NUM_WORDS 2048                 // int32 words per row
#define ROW_BYTES (NUM_WORDS * 4)      // 8192
#define VECS_PER_ROW (NUM_WORDS / 4)   // 512 int4 per row
#define BLOCK 256

// d_ws layout: uint2 per row: .x = off0 | nor_bit (offsets are 8192-aligned,
// bit0 free), .y = off1. Max offset 32767*8192 < 2^28, fits uint32.

__global__ __launch_bounds__(BLOCK) void decode_kernel(
    const void* __restrict__ idx_raw,    // int32[rows*2] or int64[rows*2]
    const void* __restrict__ mask_raw,   // int32[rows] or uint8[rows]
    uint2* __restrict__ ws,              // [rows]
    int rows)
{
    const int row = blockIdx.x * BLOCK + threadIdx.x;
    if (row >= rows) return;

    // ---- representation detection (uniform result across all threads) ----
    // nor_mask as int32: values 0/1 -> upper 31 bits always clear.
    // as byte-bool: 4 random 0/1 bytes per word -> upper bits set w.p. 7/8.
    const uint32_t* mw = (const uint32_t*)mask_raw;
    bool mask_is_i32 = true;
    #pragma unroll
    for (int i = 0; i < 32; ++i)
        if (mw[i] & ~1u) mask_is_i32 = false;

    // idx as int64: odd 32-bit words all zero (values < 2^15).
    // as int32: odd words are random in [0,32768).
    const uint32_t* iw = (const uint32_t*)idx_raw;
    bool idx_is_i64 = true;
    #pragma unroll
    for (int i = 0; i < 16; ++i)
        if (iw[2 * i + 1] != 0u) idx_is_i64 = false;

    uint32_t i0, i1;
    if (idx_is_i64) {
        const long long* ip = (const long long*)idx_raw;
        i0 = (uint32_t)ip[2 * (long)row];
        i1 = (uint32_t)ip[2 * (long)row + 1];
    } else {
        const int* ip = (const int*)idx_raw;
        i0 = (uint32_t)ip[2 * row];
        i1 = (uint32_t)ip[2 * row + 1];
    }
    uint32_t nor;
    if (mask_is_i32) nor = ((const uint32_t*)mask_raw)[row] != 0u;
    else             nor = ((const uint8_t*)mask_raw)[row] != 0u;

    uint2 e;
    e.x = i0 * ROW_BYTES + nor;
    e.y = i1 * ROW_BYTES;
    ws[row] = e;
}

__global__ __launch_bounds__(BLOCK) void nand_layer_kernel(
    const char* __restrict__ in_bits,    // base of [num_inputs * 8192] bytes
    const uint2* __restrict__ ws,        // [rows] packed {off0|nor, off1}
    int4v* __restrict__ out)             // [rows * VECS_PER_ROW]
{
    const int row = blockIdx.x;
    const uint2 e = ws[row];             // uniform address -> scalar load
    const uint32_t nor = e.x & 1u;

    const int4v* __restrict__ a = (const int4v*)(in_bits + (e.x & ~1u));
    const int4v* __restrict__ b = (const int4v*)(in_bits + e.y);
    int4v* __restrict__ o = out + (long)row * VECS_PER_ROW;

    const int t = threadIdx.x;
    #pragma unroll
    for (int k = 0; k < VECS_PER_ROW / BLOCK; ++k) {
        const int j = t + k * BLOCK;
        int4v av = a[j];
        int4v bv = b[j];
        int4v r = nor ? ~(av | bv) : ~(av & bv);
        // output is write-once, never re-read: stream past L2 so the gathered
        // input (256 MiB, ~2x reuse) keeps the cache.
        __builtin_nontemporal_store(r, &o[j]);
    }
}

extern "C" void kernel_launch(void* const* d_in, const int* in_sizes, int n_in,
                              void* d_out, int out_size, void* d_ws, size_t ws_size,
                              hipStream_t stream) {
    (void)n_in; (void)ws_size; (void)out_size;
    const int rows = in_sizes[2];                 // NUM_OUTPUTS (nor_mask count)
    const char* in_bits  = (const char*)d_in[0];
    const void* idx_raw  = d_in[1];
    const void* mask_raw = d_in[2];
    uint2* ws = (uint2*)d_ws;
    int4v* out = (int4v*)d_out;

    decode_kernel<<<(rows + BLOCK - 1) / BLOCK, BLOCK, 0, stream>>>(
        idx_raw, mask_raw, ws, rows);
    nand_layer_kernel<<<rows, BLOCK, 0, stream>>>(in_bits, ws, out);
}